// Round 5
// baseline (2431.541 us; speedup 1.0000x reference)
//
#include <hip/hip_runtime.h>
#include <stdint.h>

// Problem constants (setup_inputs: T=4096, B=4096, C=2)
#define T_STEPS 4096
#define B_SIZE  4096
#define NWORDS  (T_STEPS / 32)         // 128 packed words of 32 timesteps each
#define TB      ((size_t)T_STEPS * B_SIZE)
#define GRP     8                      // scan publishes checkpoints per 8 words
#define NGRP    (NWORDS / GRP)         // 16 groups

// BETA_MEM = 0.9, BETA_INH = 0.6, THRESHOLD = 1.0
// Reference step (per batch element b):
//   cur_exc = x0*w00 + x1*w01
//   inh     = 0.6*inh + x0 ; cur_inh = w_inh*inh ; cur = cur_exc + cur_inh
//   reset   = (mem > 1) ; mem = (0.9*mem + cur) - reset ; spk = (mem > 1)
// Outputs: spk_rec, exc_rec(=cur_exc), inh_rec(=cur_inh), mem_rec, each (T,B).
//
// ROUND-4 FINDING: the 1-GiB fillBufferAligned dispatches (165 us each) in the
// timed graph are UNCONDITIONAL harness re-poisoning (ws-using R3 == ws-free R4
// at 425 us). So d_ws is free to use, and the only controllable time is our
// ~90 us kernel slice. This round: ONE fused kernel overlapping pack (BW),
// scan (latency-bound) and replay (BW) via device-scope release/acquire flags,
// targeting the ~68 us pure-BW floor of the slice.
//
// Deadlock safety: every wait points to a producer EARLIER in program order of
// lower-indexed-or-self blocks (pack: no waits; scan waits pack; replay waits
// scan), and the whole 512-block grid is co-resident by capacity (8 waves/CU,
// no LDS, VGPR << 256), so spinning blocks can never starve producers.

// ---------------------------------------------------------------------------
// Per-step helpers — bit-identical rounding to the reference step.
// ---------------------------------------------------------------------------
__device__ __forceinline__ void step_fast(float& mem, uint32_t w1, int k, float w01,
                                          float& exc, float& spk) {
    float x1f = (float)((w1 >> k) & 1u);
    exc       = __fmul_rn(x1f, w01);              // == cur_exc exactly
    float r   = (mem > 1.0f) ? 1.0f : 0.0f;
    float m1  = __fmul_rn(0.9f, mem);
    float m2  = __fmaf_rn(x1f, w01, m1);          // identical rounding to add
    mem       = __fsub_rn(m2, r);
    spk       = (mem > 1.0f) ? 1.0f : 0.0f;
}

__device__ __forceinline__ void step_gen(float& mem, float& inh,
                                         uint32_t w0, uint32_t w1, int k,
                                         float w00, float w01, float winh,
                                         float& exc, float& ci, float& spk) {
    float x0f = (float)((w0 >> k) & 1u);
    float x1f = (float)((w1 >> k) & 1u);
    exc       = __fadd_rn(__fmul_rn(x0f, w00), __fmul_rn(x1f, w01));
    inh       = __fadd_rn(__fmul_rn(0.6f, inh), x0f);
    ci        = __fmul_rn(winh, inh);
    float cur = __fadd_rn(exc, ci);
    float r   = (mem > 1.0f) ? 1.0f : 0.0f;
    float m1  = __fmul_rn(0.9f, mem);
    float m2  = __fadd_rn(m1, cur);
    mem       = __fsub_rn(m2, r);
    spk       = (mem > 1.0f) ? 1.0f : 0.0f;
}

// ---------------------------------------------------------------------------
// Fused kernel: 512 blocks x 256 threads.
//  Phase P (all blocks): pack word i = blk>>2, quarter q = blk&3 (512 pair-
//    units per block, 2 per thread), publish packcnt[i] (target 4).
//  Phase S (blocks 0-15): serial scan; per word: spin packcnt[i]==4, load
//    words, store checkpoints, compute 32 steps; publish scancnt[i/GRP]
//    (target 16) once per 8-word group (amortizes the device-release fence).
//  Phase R (all blocks): replay one (word, quarter): rr = blk>=16 ? blk-16
//    : blk+496 (scan blocks take the LAST words, ready latest); spin
//    scancnt[i/GRP]==16, then 32 steps of float4 output stores.
// Happens-before chain pack->scan->replay is transitive, so replay's reads of
// p0/p1 and checkpoints are covered across XCDs.
// ---------------------------------------------------------------------------
__global__ __launch_bounds__(256) void k_fused(const float4* __restrict__ x,
                                               const float* __restrict__ w_exc,
                                               const float* __restrict__ w_inh_p,
                                               uint32_t* __restrict__ p0,
                                               uint32_t* __restrict__ p1,
                                               float* __restrict__ mem_ck,
                                               float* __restrict__ inh_ck,
                                               uint32_t* __restrict__ packcnt,
                                               uint32_t* __restrict__ scancnt,
                                               float* __restrict__ out) {
    const uint32_t tid = threadIdx.x, blk = blockIdx.x;
    const float w00 = w_exc[0], w01 = w_exc[1], winh = w_inh_p[0];
    const bool fast = (w00 == 0.0f && winh == 0.0f);

    // ---------------- Phase P: pack ----------------
    {
        uint32_t i = blk >> 2, q = blk & 3u;
#pragma unroll
        for (int u = 0; u < 2; ++u) {
            uint32_t bh = q * 512u + (uint32_t)u * 256u + tid;   // pair-unit
            const float4* xp = x + (size_t)i * 32u * (B_SIZE / 2) + bh;
            uint32_t a0 = 0u, a1 = 0u, b0 = 0u, b1 = 0u;
#pragma unroll
            for (int k = 0; k < 32; ++k) {
                float4 v = xp[(size_t)k * (B_SIZE / 2)];
                a0 |= (uint32_t)(v.x != 0.0f) << k;
                a1 |= (uint32_t)(v.y != 0.0f) << k;
                b0 |= (uint32_t)(v.z != 0.0f) << k;
                b1 |= (uint32_t)(v.w != 0.0f) << k;
            }
            size_t o = (size_t)i * B_SIZE + 2u * bh;
            *(uint2*)&p0[o] = make_uint2(a0, b0);
            *(uint2*)&p1[o] = make_uint2(a1, b1);
        }
        __threadfence();          // device-scope: make stores visible pre-flag
        __syncthreads();
        if (tid == 0)
            __hip_atomic_fetch_add(&packcnt[i], 1u, __ATOMIC_RELEASE,
                                   __HIP_MEMORY_SCOPE_AGENT);
    }

    // ---------------- Phase S: scan (blocks 0-15) ----------------
    if (blk < 16u) {
        const int b = (int)(blk * 256u + tid);
        float mem = 0.0f, inh = 0.0f;
        for (int g = 0; g < NGRP; ++g) {
            for (int j = 0; j < GRP; ++j) {
                int i = g * GRP + j;
                // all threads spin (broadcast load) -> no syncthreads needed
                while (__hip_atomic_load(&packcnt[i], __ATOMIC_ACQUIRE,
                                         __HIP_MEMORY_SCOPE_AGENT) < 4u)
                    __builtin_amdgcn_s_sleep(1);
                size_t o = (size_t)i * B_SIZE + b;
                uint32_t w1 = p1[o];
                uint32_t w0 = fast ? 0u : p0[o];
                mem_ck[o] = mem;                     // state BEFORE word i
                if (!fast) inh_ck[o] = inh;
                if (fast) {
#pragma unroll
                    for (int k = 0; k < 32; ++k) {
                        float x1f = (float)((w1 >> k) & 1u);
                        float r   = (mem > 1.0f) ? 1.0f : 0.0f;
                        float m1  = __fmul_rn(0.9f, mem);
                        float m2  = __fmaf_rn(x1f, w01, m1);
                        mem       = __fsub_rn(m2, r);
                    }
                } else {
#pragma unroll
                    for (int k = 0; k < 32; ++k) {
                        float x0f = (float)((w0 >> k) & 1u);
                        float x1f = (float)((w1 >> k) & 1u);
                        float exc = __fadd_rn(__fmul_rn(x0f, w00), __fmul_rn(x1f, w01));
                        inh       = __fadd_rn(__fmul_rn(0.6f, inh), x0f);
                        float ci  = __fmul_rn(winh, inh);
                        float cur = __fadd_rn(exc, ci);
                        float r   = (mem > 1.0f) ? 1.0f : 0.0f;
                        float m1  = __fmul_rn(0.9f, mem);
                        float m2  = __fadd_rn(m1, cur);
                        mem       = __fsub_rn(m2, r);
                    }
                }
            }
            // publish this group's checkpoints (one fence per 8 words)
            __threadfence();
            __syncthreads();
            if (tid == 0)
                __hip_atomic_fetch_add(&scancnt[g], 1u, __ATOMIC_RELEASE,
                                       __HIP_MEMORY_SCOPE_AGENT);
        }
    }

    // ---------------- Phase R: replay ----------------
    {
        uint32_t rr = (blk >= 16u) ? (blk - 16u) : (blk + 496u);
        uint32_t i = rr >> 2, q = rr & 3u;
        while (__hip_atomic_load(&scancnt[i / GRP], __ATOMIC_ACQUIRE,
                                 __HIP_MEMORY_SCOPE_AGENT) < 16u)
            __builtin_amdgcn_s_sleep(8);

        uint32_t b = (q * 256u + tid) * 4u;
        float* __restrict__ spk_o = out;
        float* __restrict__ exc_o = out + TB;
        float* __restrict__ inh_o = out + 2 * TB;
        float* __restrict__ mem_o = out + 3 * TB;
        size_t slot = (size_t)i * B_SIZE + b;         // 16B-aligned (b%4==0)
        float4 mem  = *(const float4*)&mem_ck[slot];
        size_t base = (size_t)i * 32u * B_SIZE + b;

        if (fast) {
            uint4 w1 = *(const uint4*)&p1[slot];
            const float4 zero = make_float4(0.0f, 0.0f, 0.0f, 0.0f);
#pragma unroll
            for (int k = 0; k < 32; ++k) {
                float4 e, s;
                step_fast(mem.x, w1.x, k, w01, e.x, s.x);
                step_fast(mem.y, w1.y, k, w01, e.y, s.y);
                step_fast(mem.z, w1.z, k, w01, e.z, s.z);
                step_fast(mem.w, w1.w, k, w01, e.w, s.w);
                size_t idx = base + (size_t)k * B_SIZE;
                *(float4*)&spk_o[idx] = s;
                *(float4*)&exc_o[idx] = e;
                *(float4*)&inh_o[idx] = zero;         // w_inh * inh == +0
                *(float4*)&mem_o[idx] = mem;
            }
        } else {
            float4 inh = *(const float4*)&inh_ck[slot];
            uint4 w0 = *(const uint4*)&p0[slot];
            uint4 w1 = *(const uint4*)&p1[slot];
#pragma unroll
            for (int k = 0; k < 32; ++k) {
                float4 e, c, s;
                step_gen(mem.x, inh.x, w0.x, w1.x, k, w00, w01, winh, e.x, c.x, s.x);
                step_gen(mem.y, inh.y, w0.y, w1.y, k, w00, w01, winh, e.y, c.y, s.y);
                step_gen(mem.z, inh.z, w0.z, w1.z, k, w00, w01, winh, e.z, c.z, s.z);
                step_gen(mem.w, inh.w, w0.w, w1.w, k, w00, w01, winh, e.w, c.w, s.w);
                size_t idx = base + (size_t)k * B_SIZE;
                *(float4*)&spk_o[idx] = s;
                *(float4*)&exc_o[idx] = e;
                *(float4*)&inh_o[idx] = c;
                *(float4*)&mem_o[idx] = mem;
            }
        }
    }
}

// ===========================================================================
// Fallback (verified in Round 4): workspace-free 3-kernel pipeline with the
// scratch stashed at the t=32*i rows of each output record (stride CKS).
// ===========================================================================
#define CKS (32u * B_SIZE)

__global__ __launch_bounds__(256) void k_pack_fb(const float4* __restrict__ x,
                                                 uint32_t* __restrict__ p0,
                                                 uint32_t* __restrict__ p1) {
    uint32_t gid = blockIdx.x * 256u + threadIdx.x;
    uint32_t i  = gid >> 11;
    uint32_t bh = gid & (B_SIZE / 2 - 1);
    const float4* xp = x + (size_t)i * 32u * (B_SIZE / 2) + bh;
    uint32_t a0 = 0u, a1 = 0u, b0 = 0u, b1 = 0u;
#pragma unroll
    for (int k = 0; k < 32; ++k) {
        float4 v = xp[(size_t)k * (B_SIZE / 2)];
        a0 |= (uint32_t)(v.x != 0.0f) << k;
        a1 |= (uint32_t)(v.y != 0.0f) << k;
        b0 |= (uint32_t)(v.z != 0.0f) << k;
        b1 |= (uint32_t)(v.w != 0.0f) << k;
    }
    size_t o = (size_t)i * CKS + 2u * bh;
    *(uint2*)&p0[o] = make_uint2(a0, b0);
    *(uint2*)&p1[o] = make_uint2(a1, b1);
}

__global__ __launch_bounds__(256) void k_scan_fb(const uint32_t* __restrict__ p0,
                                                 const uint32_t* __restrict__ p1,
                                                 const float* __restrict__ w_exc,
                                                 const float* __restrict__ w_inh_p,
                                                 float* __restrict__ mem_ck,
                                                 float* __restrict__ inh_ck) {
    int b = blockIdx.x * 256 + threadIdx.x;
    const float w00 = w_exc[0], w01 = w_exc[1], winh = w_inh_p[0];
    float mem = 0.0f, inh = 0.0f;
    if (w00 == 0.0f && winh == 0.0f) {
        uint32_t w1 = p1[b];
        for (int i = 0; i < NWORDS; ++i) {
            uint32_t w1n = (i + 1 < NWORDS) ? p1[(size_t)(i + 1) * CKS + b] : 0u;
            mem_ck[(size_t)i * CKS + b] = mem;
#pragma unroll
            for (int k = 0; k < 32; ++k) {
                float x1f = (float)((w1 >> k) & 1u);
                float r   = (mem > 1.0f) ? 1.0f : 0.0f;
                float m1  = __fmul_rn(0.9f, mem);
                float m2  = __fmaf_rn(x1f, w01, m1);
                mem       = __fsub_rn(m2, r);
            }
            w1 = w1n;
        }
    } else {
        uint32_t w0 = p0[b], w1 = p1[b];
        for (int i = 0; i < NWORDS; ++i) {
            uint32_t w0n = (i + 1 < NWORDS) ? p0[(size_t)(i + 1) * CKS + b] : 0u;
            uint32_t w1n = (i + 1 < NWORDS) ? p1[(size_t)(i + 1) * CKS + b] : 0u;
            mem_ck[(size_t)i * CKS + b] = mem;
            inh_ck[(size_t)i * CKS + b] = inh;
#pragma unroll
            for (int k = 0; k < 32; ++k) {
                float x0f = (float)((w0 >> k) & 1u);
                float x1f = (float)((w1 >> k) & 1u);
                float exc = __fadd_rn(__fmul_rn(x0f, w00), __fmul_rn(x1f, w01));
                inh       = __fadd_rn(__fmul_rn(0.6f, inh), x0f);
                float ci  = __fmul_rn(winh, inh);
                float cur = __fadd_rn(exc, ci);
                float r   = (mem > 1.0f) ? 1.0f : 0.0f;
                float m1  = __fmul_rn(0.9f, mem);
                float m2  = __fadd_rn(m1, cur);
                mem       = __fsub_rn(m2, r);
            }
            w0 = w0n; w1 = w1n;
        }
    }
}

__global__ __launch_bounds__(256) void k_replay_fb(const uint32_t* p0,
                                                   const uint32_t* p1,
                                                   const float* __restrict__ w_exc,
                                                   const float* __restrict__ w_inh_p,
                                                   const float* mem_ck,
                                                   const float* inh_ck,
                                                   float* out) {
    uint32_t gid = blockIdx.x * 256u + threadIdx.x;
    uint32_t i  = gid >> 10;
    uint32_t bq = gid & (B_SIZE / 4 - 1);
    uint32_t b  = bq * 4u;
    float* spk_o = out;
    float* exc_o = out + TB;
    float* inh_o = out + 2 * TB;
    float* mem_o = out + 3 * TB;
    const float w00 = w_exc[0], w01 = w_exc[1], winh = w_inh_p[0];
    size_t slot = (size_t)i * CKS + b;
    float4 mem  = *(const float4*)&mem_ck[slot];
    size_t base = (size_t)i * 32u * B_SIZE + b;
    if (w00 == 0.0f && winh == 0.0f) {
        uint4 w1 = *(const uint4*)&p1[slot];
        const float4 zero = make_float4(0.0f, 0.0f, 0.0f, 0.0f);
#pragma unroll
        for (int k = 0; k < 32; ++k) {
            float4 e, s;
            step_fast(mem.x, w1.x, k, w01, e.x, s.x);
            step_fast(mem.y, w1.y, k, w01, e.y, s.y);
            step_fast(mem.z, w1.z, k, w01, e.z, s.z);
            step_fast(mem.w, w1.w, k, w01, e.w, s.w);
            size_t idx = base + (size_t)k * B_SIZE;
            *(float4*)&spk_o[idx] = s;
            *(float4*)&exc_o[idx] = e;
            *(float4*)&inh_o[idx] = zero;
            *(float4*)&mem_o[idx] = mem;
        }
    } else {
        float4 inh = *(const float4*)&inh_ck[slot];
        uint4 w0 = *(const uint4*)&p0[slot];
        uint4 w1 = *(const uint4*)&p1[slot];
#pragma unroll
        for (int k = 0; k < 32; ++k) {
            float4 e, c, s;
            step_gen(mem.x, inh.x, w0.x, w1.x, k, w00, w01, winh, e.x, c.x, s.x);
            step_gen(mem.y, inh.y, w0.y, w1.y, k, w00, w01, winh, e.y, c.y, s.y);
            step_gen(mem.z, inh.z, w0.z, w1.z, k, w00, w01, winh, e.z, c.z, s.z);
            step_gen(mem.w, inh.w, w0.w, w1.w, k, w00, w01, winh, e.w, c.w, s.w);
            size_t idx = base + (size_t)k * B_SIZE;
            *(float4*)&spk_o[idx] = s;
            *(float4*)&exc_o[idx] = e;
            *(float4*)&inh_o[idx] = c;
            *(float4*)&mem_o[idx] = mem;
        }
    }
}

extern "C" void kernel_launch(void* const* d_in, const int* in_sizes, int n_in,
                              void* d_out, int out_size, void* d_ws, size_t ws_size,
                              hipStream_t stream) {
    const float4* x4    = (const float4*)d_in[0];   // (T,B,2) f32, read as pairs
    const float*  w_exc = (const float*)d_in[1];    // (1,2) f32
    const float*  w_inh = (const float*)d_in[2];    // scalar f32
    float* out = (float*)d_out;

    const size_t nw = (size_t)NWORDS * B_SIZE;      // 512K elements per array
    const size_t need = nw * 16 + (NWORDS + NGRP) * sizeof(uint32_t); // 8MiB + flags

    if (ws_size >= need) {
        uint32_t* p0      = (uint32_t*)d_ws;
        uint32_t* p1      = p0 + nw;
        float*    mem_ck  = (float*)(p1 + nw);
        float*    inh_ck  = mem_ck + nw;
        uint32_t* packcnt = (uint32_t*)(inh_ck + nw);
        uint32_t* scancnt = packcnt + NWORDS;
        // zero the flags (captured in the graph -> re-runs every iteration,
        // also undoing the harness's ws poison on this 576-B region)
        hipMemsetAsync(packcnt, 0, (NWORDS + NGRP) * sizeof(uint32_t), stream);
        k_fused<<<512, 256, 0, stream>>>(x4, w_exc, w_inh, p0, p1,
                                         mem_ck, inh_ck, packcnt, scancnt, out);
    } else {
        // Verified R4 fallback: scratch inside the output buffer, 3 kernels.
        uint32_t* p0     = (uint32_t*)out;
        uint32_t* p1     = (uint32_t*)(out + TB);
        float*    inh_ck = out + 2 * TB;
        float*    mem_ck = out + 3 * TB;
        k_pack_fb<<<(NWORDS * (B_SIZE / 2)) / 256, 256, 0, stream>>>(x4, p0, p1);
        k_scan_fb<<<B_SIZE / 256, 256, 0, stream>>>(p0, p1, w_exc, w_inh, mem_ck, inh_ck);
        k_replay_fb<<<(NWORDS * (B_SIZE / 4)) / 256, 256, 0, stream>>>(p0, p1, w_exc, w_inh,
                                                                       mem_ck, inh_ck, out);
    }
}

// Round 8
// 735.400 us; speedup vs baseline: 3.3064x; 3.3064x over previous
//
#include <hip/hip_runtime.h>
#include <stdint.h>

// Problem constants (setup_inputs: T=4096, B=4096, C=2)
#define T_STEPS 4096
#define B_SIZE  4096
#define NWORDS  (T_STEPS / 32)         // 128 packed words of 32 timesteps each
#define TB      ((size_t)T_STEPS * B_SIZE)
#define PADW    16                     // uint32 per flag slot (64 B padding)

// BETA_MEM = 0.9, BETA_INH = 0.6, THRESHOLD = 1.0. Per-step (batch elem b):
//   exc = x0*w00 + x1*w01 ; inh = 0.6*inh + x0 ; ci = w_inh*inh
//   cur = exc + ci ; r = (mem>1) ; mem = (0.9*mem + cur) - r ; spk = (mem>1)
//
// R5 POST-MORTEM: fused 3-phase kernel hit 2194 us with VALUBusy 0.44% —
// 128k threads spinning per-lane device-scope atomic loads on ~2 cachelines
// swamped the flag-home L2 bank. Sync was CORRECT (passed), just toxic.
// R6/R7 DESIGN: only pack->scan is flag-synced (16 spinning lanes total, each
// on its own 64-B flag, s_sleep backoff, tid0-acquire + __syncthreads
// broadcast). Replay is a separate kernel (launch boundary = scan->replay
// dependency). Pack waits on nothing; scan waits only on pack => deadlock-free
// under any block scheduling; worst case degrades to R4's serialized ~425 us.
// R7 PRE-FLIGHT FIX: tid0 PRE-ISSUES a relaxed load of flag[i+1] before
// computing word i, then upgrades with an acquire fence (or falls back to the
// acquire spin). Keeps the ~0.2us flag round-trip OFF the serial scan chain.

// ---------------------------------------------------------------------------
// Per-step helpers — bit-identical rounding to the reference step.
// ---------------------------------------------------------------------------
__device__ __forceinline__ void step_fast(float& mem, uint32_t w1, int k, float w01,
                                          float& exc, float& spk) {
    float x1f = (float)((w1 >> k) & 1u);
    exc       = __fmul_rn(x1f, w01);              // == cur_exc exactly
    float r   = (mem > 1.0f) ? 1.0f : 0.0f;
    float m1  = __fmul_rn(0.9f, mem);
    float m2  = __fmaf_rn(x1f, w01, m1);          // identical rounding to add
    mem       = __fsub_rn(m2, r);
    spk       = (mem > 1.0f) ? 1.0f : 0.0f;
}

__device__ __forceinline__ void step_gen(float& mem, float& inh,
                                         uint32_t w0, uint32_t w1, int k,
                                         float w00, float w01, float winh,
                                         float& exc, float& ci, float& spk) {
    float x0f = (float)((w0 >> k) & 1u);
    float x1f = (float)((w1 >> k) & 1u);
    exc       = __fadd_rn(__fmul_rn(x0f, w00), __fmul_rn(x1f, w01));
    inh       = __fadd_rn(__fmul_rn(0.6f, inh), x0f);
    ci        = __fmul_rn(winh, inh);
    float cur = __fadd_rn(exc, ci);
    float r   = (mem > 1.0f) ? 1.0f : 0.0f;
    float m1  = __fmul_rn(0.9f, mem);
    float m2  = __fadd_rn(m1, cur);
    mem       = __fsub_rn(m2, r);
    spk       = (mem > 1.0f) ? 1.0f : 0.0f;
}

// ---------------------------------------------------------------------------
// Kernel A: pack + scan overlapped. Grid = 16 scan blocks + 1024 pack blocks.
//  Pack block (i,sub): packs columns [512*sub, 512*sub+512) of word i, then
//    release-stores flags[(i*8+sub)*PADW] = 1 (own 64-B line).
//  Scan block s (0..15): serial scan of columns [256s, 256s+256); per word i
//    needs exactly pack sub-block sub = s>>1. tid0 pre-issues a relaxed load
//    of the NEXT word's flag before computing the current word, so the flag
//    round-trip hides under the FP chain; __syncthreads broadcasts readiness.
//    16 polling lanes total, each on its own 64-B line, s_sleep backoff.
// ---------------------------------------------------------------------------
__global__ __launch_bounds__(256) void k_pack_scan(const float4* __restrict__ x,
                                                   const float* __restrict__ w_exc,
                                                   const float* __restrict__ w_inh_p,
                                                   uint32_t* __restrict__ p0,
                                                   uint32_t* __restrict__ p1,
                                                   float* __restrict__ mem_ck,
                                                   float* __restrict__ inh_ck,
                                                   uint32_t* __restrict__ flags) {
    const uint32_t tid = threadIdx.x, blk = blockIdx.x;

    if (blk >= 16u) {
        // ---------------- pack role ----------------
        uint32_t pb = blk - 16u;
        uint32_t i = pb >> 3, sub = pb & 7u;
        uint32_t bh = sub * 256u + tid;               // pair-unit (2 columns)
        const float4* xp = x + (size_t)i * 32u * (B_SIZE / 2) + bh;
        uint32_t a0 = 0u, a1 = 0u, b0 = 0u, b1 = 0u;
#pragma unroll
        for (int k = 0; k < 32; ++k) {
            float4 v = xp[(size_t)k * (B_SIZE / 2)];
            a0 |= (uint32_t)(v.x != 0.0f) << k;
            a1 |= (uint32_t)(v.y != 0.0f) << k;
            b0 |= (uint32_t)(v.z != 0.0f) << k;
            b1 |= (uint32_t)(v.w != 0.0f) << k;
        }
        size_t o = (size_t)i * B_SIZE + 2u * bh;
        *(uint2*)&p0[o] = make_uint2(a0, b0);
        *(uint2*)&p1[o] = make_uint2(a1, b1);
        __threadfence();                  // each thread publishes its stores
        __syncthreads();                  // all fences done before the flag
        if (tid == 0)
            __hip_atomic_store(&flags[(i * 8u + sub) * PADW], 1u,
                               __ATOMIC_RELEASE, __HIP_MEMORY_SCOPE_AGENT);
        return;
    }

    // ---------------- scan role (blocks 0-15) ----------------
    const float w00 = w_exc[0], w01 = w_exc[1], winh = w_inh_p[0];
    const bool fast = (w00 == 0.0f && winh == 0.0f);
    const uint32_t s = blk;
    const int b = (int)(s * 256u + tid);
    const uint32_t sub = s >> 1;                      // pack sub-block we need
    float mem = 0.0f, inh = 0.0f;

    // Acquire word 0's flag before the loop.
    if (tid == 0) {
        while (__hip_atomic_load(&flags[sub * PADW], __ATOMIC_ACQUIRE,
                                 __HIP_MEMORY_SCOPE_AGENT) == 0u)
            __builtin_amdgcn_s_sleep(2);
    }
    __syncthreads();

    for (int i = 0; i < NWORDS; ++i) {
        // Pre-issue next word's flag check (independent of the FP chain, so
        // it overlaps with this word's compute).
        uint32_t pre = 1u;
        if (tid == 0 && i + 1 < NWORDS)
            pre = __hip_atomic_load(&flags[((uint32_t)(i + 1) * 8u + sub) * PADW],
                                    __ATOMIC_RELAXED, __HIP_MEMORY_SCOPE_AGENT);

        size_t o = (size_t)i * B_SIZE + b;
        uint32_t w1 = p1[o];
        uint32_t w0 = fast ? 0u : p0[o];
        mem_ck[o] = mem;                  // exact state BEFORE word i
        if (!fast) inh_ck[o] = inh;
        if (fast) {
#pragma unroll
            for (int k = 0; k < 32; ++k) {
                float x1f = (float)((w1 >> k) & 1u);
                float r   = (mem > 1.0f) ? 1.0f : 0.0f;
                float m1  = __fmul_rn(0.9f, mem);
                float m2  = __fmaf_rn(x1f, w01, m1);
                mem       = __fsub_rn(m2, r);
            }
        } else {
#pragma unroll
            for (int k = 0; k < 32; ++k) {
                float x0f = (float)((w0 >> k) & 1u);
                float x1f = (float)((w1 >> k) & 1u);
                float exc = __fadd_rn(__fmul_rn(x0f, w00), __fmul_rn(x1f, w01));
                inh       = __fadd_rn(__fmul_rn(0.6f, inh), x0f);
                float ci  = __fmul_rn(winh, inh);
                float cur = __fadd_rn(exc, ci);
                float r   = (mem > 1.0f) ? 1.0f : 0.0f;
                float m1  = __fmul_rn(0.9f, mem);
                float m2  = __fadd_rn(m1, cur);
                mem       = __fsub_rn(m2, r);
            }
        }

        // Commit next word's readiness: fast path = relaxed load saw 1 ->
        // acquire fence gives synchronizes-with; slow path = acquire spin.
        if (tid == 0 && i + 1 < NWORDS) {
            if (pre != 0u) {
                __threadfence();          // acquire upgrade of the relaxed read
            } else {
                while (__hip_atomic_load(&flags[((uint32_t)(i + 1) * 8u + sub) * PADW],
                                         __ATOMIC_ACQUIRE,
                                         __HIP_MEMORY_SCOPE_AGENT) == 0u)
                    __builtin_amdgcn_s_sleep(2);
            }
        }
        __syncthreads();                  // broadcast readiness of word i+1
    }
}

// ---------------------------------------------------------------------------
// Kernel B: replay (dense ws layout, stride B). One thread per (word, batch
// quad); float4 output stores. ws arrays are disjoint from out -> restrict.
// Kernel-boundary ordering guarantees scan's checkpoints are visible.
// ---------------------------------------------------------------------------
__global__ __launch_bounds__(256) void k_replay(const uint32_t* __restrict__ p0,
                                                const uint32_t* __restrict__ p1,
                                                const float* __restrict__ w_exc,
                                                const float* __restrict__ w_inh_p,
                                                const float* __restrict__ mem_ck,
                                                const float* __restrict__ inh_ck,
                                                float* __restrict__ out) {
    uint32_t gid = blockIdx.x * 256u + threadIdx.x;   // NWORDS * B/4 threads
    uint32_t i  = gid >> 10;                          // word index (B/4 == 1024)
    uint32_t b  = (gid & (B_SIZE / 4 - 1)) * 4u;
    float* __restrict__ spk_o = out;
    float* __restrict__ exc_o = out + TB;
    float* __restrict__ inh_o = out + 2 * TB;
    float* __restrict__ mem_o = out + 3 * TB;
    const float w00 = w_exc[0], w01 = w_exc[1], winh = w_inh_p[0];
    size_t slot = (size_t)i * B_SIZE + b;             // 16B-aligned
    float4 mem  = *(const float4*)&mem_ck[slot];
    size_t base = (size_t)i * 32u * B_SIZE + b;

    if (w00 == 0.0f && winh == 0.0f) {
        uint4 w1 = *(const uint4*)&p1[slot];
        const float4 zero = make_float4(0.0f, 0.0f, 0.0f, 0.0f);
#pragma unroll
        for (int k = 0; k < 32; ++k) {
            float4 e, s;
            step_fast(mem.x, w1.x, k, w01, e.x, s.x);
            step_fast(mem.y, w1.y, k, w01, e.y, s.y);
            step_fast(mem.z, w1.z, k, w01, e.z, s.z);
            step_fast(mem.w, w1.w, k, w01, e.w, s.w);
            size_t idx = base + (size_t)k * B_SIZE;
            *(float4*)&spk_o[idx] = s;
            *(float4*)&exc_o[idx] = e;
            *(float4*)&inh_o[idx] = zero;             // w_inh * inh == +0
            *(float4*)&mem_o[idx] = mem;
        }
    } else {
        float4 inh = *(const float4*)&inh_ck[slot];
        uint4 w0 = *(const uint4*)&p0[slot];
        uint4 w1 = *(const uint4*)&p1[slot];
#pragma unroll
        for (int k = 0; k < 32; ++k) {
            float4 e, c, s;
            step_gen(mem.x, inh.x, w0.x, w1.x, k, w00, w01, winh, e.x, c.x, s.x);
            step_gen(mem.y, inh.y, w0.y, w1.y, k, w00, w01, winh, e.y, c.y, s.y);
            step_gen(mem.z, inh.z, w0.z, w1.z, k, w00, w01, winh, e.z, c.z, s.z);
            step_gen(mem.w, inh.w, w0.w, w1.w, k, w00, w01, winh, e.w, c.w, s.w);
            size_t idx = base + (size_t)k * B_SIZE;
            *(float4*)&spk_o[idx] = s;
            *(float4*)&exc_o[idx] = e;
            *(float4*)&inh_o[idx] = c;
            *(float4*)&mem_o[idx] = mem;
        }
    }
}

// ===========================================================================
// Fallback (verified Round 4, 425 us): workspace-free 3-kernel pipeline with
// scratch stashed at the t=32*i rows of each output record (stride CKS).
// ===========================================================================
#define CKS (32u * B_SIZE)

__global__ __launch_bounds__(256) void k_pack_fb(const float4* __restrict__ x,
                                                 uint32_t* __restrict__ p0,
                                                 uint32_t* __restrict__ p1) {
    uint32_t gid = blockIdx.x * 256u + threadIdx.x;
    uint32_t i  = gid >> 11;
    uint32_t bh = gid & (B_SIZE / 2 - 1);
    const float4* xp = x + (size_t)i * 32u * (B_SIZE / 2) + bh;
    uint32_t a0 = 0u, a1 = 0u, b0 = 0u, b1 = 0u;
#pragma unroll
    for (int k = 0; k < 32; ++k) {
        float4 v = xp[(size_t)k * (B_SIZE / 2)];
        a0 |= (uint32_t)(v.x != 0.0f) << k;
        a1 |= (uint32_t)(v.y != 0.0f) << k;
        b0 |= (uint32_t)(v.z != 0.0f) << k;
        b1 |= (uint32_t)(v.w != 0.0f) << k;
    }
    size_t o = (size_t)i * CKS + 2u * bh;
    *(uint2*)&p0[o] = make_uint2(a0, b0);
    *(uint2*)&p1[o] = make_uint2(a1, b1);
}

__global__ __launch_bounds__(256) void k_scan_fb(const uint32_t* __restrict__ p0,
                                                 const uint32_t* __restrict__ p1,
                                                 const float* __restrict__ w_exc,
                                                 const float* __restrict__ w_inh_p,
                                                 float* __restrict__ mem_ck,
                                                 float* __restrict__ inh_ck) {
    int b = blockIdx.x * 256 + threadIdx.x;
    const float w00 = w_exc[0], w01 = w_exc[1], winh = w_inh_p[0];
    float mem = 0.0f, inh = 0.0f;
    if (w00 == 0.0f && winh == 0.0f) {
        uint32_t w1 = p1[b];
        for (int i = 0; i < NWORDS; ++i) {
            uint32_t w1n = (i + 1 < NWORDS) ? p1[(size_t)(i + 1) * CKS + b] : 0u;
            mem_ck[(size_t)i * CKS + b] = mem;
#pragma unroll
            for (int k = 0; k < 32; ++k) {
                float x1f = (float)((w1 >> k) & 1u);
                float r   = (mem > 1.0f) ? 1.0f : 0.0f;
                float m1  = __fmul_rn(0.9f, mem);
                float m2  = __fmaf_rn(x1f, w01, m1);
                mem       = __fsub_rn(m2, r);
            }
            w1 = w1n;
        }
    } else {
        uint32_t w0 = p0[b], w1 = p1[b];
        for (int i = 0; i < NWORDS; ++i) {
            uint32_t w0n = (i + 1 < NWORDS) ? p0[(size_t)(i + 1) * CKS + b] : 0u;
            uint32_t w1n = (i + 1 < NWORDS) ? p1[(size_t)(i + 1) * CKS + b] : 0u;
            mem_ck[(size_t)i * CKS + b] = mem;
            inh_ck[(size_t)i * CKS + b] = inh;
#pragma unroll
            for (int k = 0; k < 32; ++k) {
                float x0f = (float)((w0 >> k) & 1u);
                float x1f = (float)((w1 >> k) & 1u);
                float exc = __fadd_rn(__fmul_rn(x0f, w00), __fmul_rn(x1f, w01));
                inh       = __fadd_rn(__fmul_rn(0.6f, inh), x0f);
                float ci  = __fmul_rn(winh, inh);
                float cur = __fadd_rn(exc, ci);
                float r   = (mem > 1.0f) ? 1.0f : 0.0f;
                float m1  = __fmul_rn(0.9f, mem);
                float m2  = __fadd_rn(m1, cur);
                mem       = __fsub_rn(m2, r);
            }
            w0 = w0n; w1 = w1n;
        }
    }
}

__global__ __launch_bounds__(256) void k_replay_fb(const uint32_t* p0,
                                                   const uint32_t* p1,
                                                   const float* __restrict__ w_exc,
                                                   const float* __restrict__ w_inh_p,
                                                   const float* mem_ck,
                                                   const float* inh_ck,
                                                   float* out) {
    uint32_t gid = blockIdx.x * 256u + threadIdx.x;
    uint32_t i  = gid >> 10;
    uint32_t b  = (gid & (B_SIZE / 4 - 1)) * 4u;
    float* spk_o = out;
    float* exc_o = out + TB;
    float* inh_o = out + 2 * TB;
    float* mem_o = out + 3 * TB;
    const float w00 = w_exc[0], w01 = w_exc[1], winh = w_inh_p[0];
    size_t slot = (size_t)i * CKS + b;
    float4 mem  = *(const float4*)&mem_ck[slot];
    size_t base = (size_t)i * 32u * B_SIZE + b;
    if (w00 == 0.0f && winh == 0.0f) {
        uint4 w1 = *(const uint4*)&p1[slot];
        const float4 zero = make_float4(0.0f, 0.0f, 0.0f, 0.0f);
#pragma unroll
        for (int k = 0; k < 32; ++k) {
            float4 e, s;
            step_fast(mem.x, w1.x, k, w01, e.x, s.x);
            step_fast(mem.y, w1.y, k, w01, e.y, s.y);
            step_fast(mem.z, w1.z, k, w01, e.z, s.z);
            step_fast(mem.w, w1.w, k, w01, e.w, s.w);
            size_t idx = base + (size_t)k * B_SIZE;
            *(float4*)&spk_o[idx] = s;
            *(float4*)&exc_o[idx] = e;
            *(float4*)&inh_o[idx] = zero;
            *(float4*)&mem_o[idx] = mem;
        }
    } else {
        float4 inh = *(const float4*)&inh_ck[slot];
        uint4 w0 = *(const uint4*)&p0[slot];
        uint4 w1 = *(const uint4*)&p1[slot];
#pragma unroll
        for (int k = 0; k < 32; ++k) {
            float4 e, c, s;
            step_gen(mem.x, inh.x, w0.x, w1.x, k, w00, w01, winh, e.x, c.x, s.x);
            step_gen(mem.y, inh.y, w0.y, w1.y, k, w00, w01, winh, e.y, c.y, s.y);
            step_gen(mem.z, inh.z, w0.z, w1.z, k, w00, w01, winh, e.z, c.z, s.z);
            step_gen(mem.w, inh.w, w0.w, w1.w, k, w00, w01, winh, e.w, c.w, s.w);
            size_t idx = base + (size_t)k * B_SIZE;
            *(float4*)&spk_o[idx] = s;
            *(float4*)&exc_o[idx] = e;
            *(float4*)&inh_o[idx] = c;
            *(float4*)&mem_o[idx] = mem;
        }
    }
}

extern "C" void kernel_launch(void* const* d_in, const int* in_sizes, int n_in,
                              void* d_out, int out_size, void* d_ws, size_t ws_size,
                              hipStream_t stream) {
    const float4* x4    = (const float4*)d_in[0];   // (T,B,2) f32, read as pairs
    const float*  w_exc = (const float*)d_in[1];    // (1,2) f32
    const float*  w_inh = (const float*)d_in[2];    // scalar f32
    float* out = (float*)d_out;

    const size_t nw     = (size_t)NWORDS * B_SIZE;  // 512K elements per array
    const size_t flagsz = (size_t)NWORDS * 8 * PADW * sizeof(uint32_t); // 64 KiB
    const size_t need   = nw * 16 + flagsz;         // 8 MiB + flags

    if (ws_size >= need) {
        uint32_t* p0     = (uint32_t*)d_ws;
        uint32_t* p1     = p0 + nw;
        float*    mem_ck = (float*)(p1 + nw);
        float*    inh_ck = mem_ck + nw;
        uint32_t* flags  = (uint32_t*)(inh_ck + nw);
        // Zero the flags every iteration (captured in the graph). This also
        // neutralizes the harness's ws re-poison on this region — mandatory:
        // poisoned flags would be nonzero and break the wait protocol.
        hipMemsetAsync(flags, 0, flagsz, stream);
        // A: pack + scan overlapped (16 scan blocks first, then 1024 pack)
        k_pack_scan<<<16 + NWORDS * 8, 256, 0, stream>>>(x4, w_exc, w_inh,
                                                         p0, p1, mem_ck, inh_ck, flags);
        // B: replay (kernel boundary gives the scan->replay dependency)
        k_replay<<<(NWORDS * (B_SIZE / 4)) / 256, 256, 0, stream>>>(p0, p1, w_exc, w_inh,
                                                                    mem_ck, inh_ck, out);
    } else {
        // Verified R4 fallback: scratch inside the output buffer, 3 kernels.
        uint32_t* p0     = (uint32_t*)out;
        uint32_t* p1     = (uint32_t*)(out + TB);
        float*    inh_ck = out + 2 * TB;
        float*    mem_ck = out + 3 * TB;
        k_pack_fb<<<(NWORDS * (B_SIZE / 2)) / 256, 256, 0, stream>>>(x4, p0, p1);
        k_scan_fb<<<B_SIZE / 256, 256, 0, stream>>>(p0, p1, w_exc, w_inh, mem_ck, inh_ck);
        k_replay_fb<<<(NWORDS * (B_SIZE / 4)) / 256, 256, 0, stream>>>(p0, p1, w_exc, w_inh,
                                                                       mem_ck, inh_ck, out);
    }
}

// Round 13
// 429.215 us; speedup vs baseline: 5.6651x; 1.7134x over previous
//
#include <hip/hip_runtime.h>
#include <stdint.h>

// Problem constants (setup_inputs: T=4096, B=4096, C=2)
#define T_STEPS 4096
#define B_SIZE  4096
#define NWORDS  (T_STEPS / 32)         // 128 packed words of 32 timesteps each
#define TB      ((size_t)T_STEPS * B_SIZE)

// BETA_MEM = 0.9, BETA_INH = 0.6, THRESHOLD = 1.0. Per-step (batch elem b):
//   exc = x0*w00 + x1*w01 ; inh = 0.6*inh + x0 ; ci = w_inh*inh
//   cur = exc + ci ; r = (mem>1) ; mem = (0.9*mem + cur) - r ; spk = (mem>1)
// Outputs: spk_rec, exc_rec(=exc), inh_rec(=ci), mem_rec, each (T,B).
//
// SESSION FINDINGS (R3-R8):
//  * The two 1-GiB fillBufferAligned dispatches (~165 us each, 80% HBM peak)
//    in the timed graph are UNCONDITIONAL harness ws re-poisoning: R3 (ws)
//    vs R4 (ws-free) both measured 425.0 us. ~330 us is untouchable.
//  * Intra-grid producer->consumer spin pipelines FAIL on MI355X twice:
//    R5 (128k spinning threads) = 2194 us; R8 (16 hygienic spinners, 64-B
//    padded flags, relaxed pre-poll) = 423 us in k_pack_scan with VALUBusy
//    1.3% — cross-XCD release->acquire visibility is ~3 us/flag. Abandoned.
//  * Controllable slice ~95 us vs ~89 us serial floor (pack 21 = 128 MiB
//    read; scan ~25 = irreducible 4096-step nonlinear chain; replay ~48 vs
//    43 = 256 MiB write + scratch read). This file is the verified-fastest
//    serialized pipeline: dense-ws 3-kernel, float4 replay stores.

// ---------------------------------------------------------------------------
// Per-step helpers — bit-identical rounding to the reference step.
// ---------------------------------------------------------------------------
__device__ __forceinline__ void step_fast(float& mem, uint32_t w1, int k, float w01,
                                          float& exc, float& spk) {
    float x1f = (float)((w1 >> k) & 1u);
    exc       = __fmul_rn(x1f, w01);              // == cur_exc exactly
    float r   = (mem > 1.0f) ? 1.0f : 0.0f;
    float m1  = __fmul_rn(0.9f, mem);
    float m2  = __fmaf_rn(x1f, w01, m1);          // identical rounding to add
    mem       = __fsub_rn(m2, r);
    spk       = (mem > 1.0f) ? 1.0f : 0.0f;
}

__device__ __forceinline__ void step_gen(float& mem, float& inh,
                                         uint32_t w0, uint32_t w1, int k,
                                         float w00, float w01, float winh,
                                         float& exc, float& ci, float& spk) {
    float x0f = (float)((w0 >> k) & 1u);
    float x1f = (float)((w1 >> k) & 1u);
    exc       = __fadd_rn(__fmul_rn(x0f, w00), __fmul_rn(x1f, w01));
    inh       = __fadd_rn(__fmul_rn(0.6f, inh), x0f);
    ci        = __fmul_rn(winh, inh);
    float cur = __fadd_rn(exc, ci);
    float r   = (mem > 1.0f) ? 1.0f : 0.0f;
    float m1  = __fmul_rn(0.9f, mem);
    float m2  = __fadd_rn(m1, cur);
    mem       = __fsub_rn(m2, r);
    spk       = (mem > 1.0f) ? 1.0f : 0.0f;
}

// ---------------------------------------------------------------------------
// K0: pack spike bits (dense ws layout, stride B). x is (T,B,2) f32 with
// values exactly 0.0 or 1.0. Each thread packs TWO batch elements via float4
// loads (16 B/lane). [harness-verified in R3]
// ---------------------------------------------------------------------------
__global__ __launch_bounds__(256) void k_pack(const float4* __restrict__ x,
                                              uint32_t* __restrict__ p0,
                                              uint32_t* __restrict__ p1) {
    uint32_t gid = blockIdx.x * 256u + threadIdx.x;   // NWORDS * B/2 threads
    uint32_t i  = gid >> 11;                          // word index (B/2 == 2048)
    uint32_t bh = gid & (B_SIZE / 2 - 1);             // batch-pair index
    const float4* xp = x + (size_t)i * 32u * (B_SIZE / 2) + bh;
    uint32_t a0 = 0u, a1 = 0u, b0 = 0u, b1 = 0u;
#pragma unroll
    for (int k = 0; k < 32; ++k) {
        float4 v = xp[(size_t)k * (B_SIZE / 2)];
        a0 |= (uint32_t)(v.x != 0.0f) << k;   // b = 2*bh,   channel 0
        a1 |= (uint32_t)(v.y != 0.0f) << k;   // b = 2*bh,   channel 1
        b0 |= (uint32_t)(v.z != 0.0f) << k;   // b = 2*bh+1, channel 0
        b1 |= (uint32_t)(v.w != 0.0f) << k;   // b = 2*bh+1, channel 1
    }
    size_t o = (size_t)i * B_SIZE + 2u * bh;  // even -> 8B-aligned uint2 store
    *(uint2*)&p0[o] = make_uint2(a0, b0);
    *(uint2*)&p1[o] = make_uint2(a1, b1);
}

// ---------------------------------------------------------------------------
// K1: serial scan over T per batch element, from packed bits (4 MiB, cached).
// Writes exact state checkpoints (mem, inh) BEFORE each 32-step word.
// [harness-verified in R3]
// ---------------------------------------------------------------------------
__global__ __launch_bounds__(256) void k_scan(const uint32_t* __restrict__ p0,
                                              const uint32_t* __restrict__ p1,
                                              const float* __restrict__ w_exc,
                                              const float* __restrict__ w_inh_p,
                                              float* __restrict__ mem_ck,
                                              float* __restrict__ inh_ck) {
    int b = blockIdx.x * 256 + threadIdx.x;
    const float w00 = w_exc[0], w01 = w_exc[1], winh = w_inh_p[0];
    float mem = 0.0f, inh = 0.0f;

    if (w00 == 0.0f && winh == 0.0f) {
        // Fast path: cur = w01*x1 exactly; inh does not affect mem.
        uint32_t w1 = p1[b];
        for (int i = 0; i < NWORDS; ++i) {
            uint32_t w1n = (i + 1 < NWORDS) ? p1[(size_t)(i + 1) * B_SIZE + b] : 0u;
            mem_ck[(size_t)i * B_SIZE + b] = mem;
#pragma unroll
            for (int k = 0; k < 32; ++k) {
                float x1f = (float)((w1 >> k) & 1u);
                float r   = (mem > 1.0f) ? 1.0f : 0.0f;  // old-mem reset
                float m1  = __fmul_rn(0.9f, mem);
                // x1f*w01 is exact (x in {0,1}) -> fma == round(m1 + cur).
                float m2  = __fmaf_rn(x1f, w01, m1);
                mem       = __fsub_rn(m2, r);
            }
            w1 = w1n;
        }
    } else {
        uint32_t w0 = p0[b], w1 = p1[b];
        for (int i = 0; i < NWORDS; ++i) {
            uint32_t w0n = (i + 1 < NWORDS) ? p0[(size_t)(i + 1) * B_SIZE + b] : 0u;
            uint32_t w1n = (i + 1 < NWORDS) ? p1[(size_t)(i + 1) * B_SIZE + b] : 0u;
            mem_ck[(size_t)i * B_SIZE + b] = mem;
            inh_ck[(size_t)i * B_SIZE + b] = inh;
#pragma unroll
            for (int k = 0; k < 32; ++k) {
                float x0f = (float)((w0 >> k) & 1u);
                float x1f = (float)((w1 >> k) & 1u);
                float exc = __fadd_rn(__fmul_rn(x0f, w00), __fmul_rn(x1f, w01));
                inh       = __fadd_rn(__fmul_rn(0.6f, inh), x0f);
                float ci  = __fmul_rn(winh, inh);
                float cur = __fadd_rn(exc, ci);
                float r   = (mem > 1.0f) ? 1.0f : 0.0f;
                float m1  = __fmul_rn(0.9f, mem);
                float m2  = __fadd_rn(m1, cur);
                mem       = __fsub_rn(m2, r);
            }
            w0 = w0n; w1 = w1n;
        }
    }
}

// ---------------------------------------------------------------------------
// K2: parallel replay (dense ws layout). One thread per (word, batch QUAD);
// starts from exact checkpoints, writes all 4 records via float4 stores
// (16 B/lane — HBM sweet spot; K2 writes all 256 MiB of output).
// [harness-verified: ran & passed inside R8]
// ---------------------------------------------------------------------------
__global__ __launch_bounds__(256) void k_replay(const uint32_t* __restrict__ p0,
                                                const uint32_t* __restrict__ p1,
                                                const float* __restrict__ w_exc,
                                                const float* __restrict__ w_inh_p,
                                                const float* __restrict__ mem_ck,
                                                const float* __restrict__ inh_ck,
                                                float* __restrict__ out) {
    uint32_t gid = blockIdx.x * 256u + threadIdx.x;   // NWORDS * B/4 threads
    uint32_t i  = gid >> 10;                          // word index (B/4 == 1024)
    uint32_t b  = (gid & (B_SIZE / 4 - 1)) * 4u;
    float* __restrict__ spk_o = out;
    float* __restrict__ exc_o = out + TB;
    float* __restrict__ inh_o = out + 2 * TB;
    float* __restrict__ mem_o = out + 3 * TB;
    const float w00 = w_exc[0], w01 = w_exc[1], winh = w_inh_p[0];
    size_t slot = (size_t)i * B_SIZE + b;             // 16B-aligned
    float4 mem  = *(const float4*)&mem_ck[slot];
    size_t base = (size_t)i * 32u * B_SIZE + b;

    if (w00 == 0.0f && winh == 0.0f) {
        uint4 w1 = *(const uint4*)&p1[slot];
        const float4 zero = make_float4(0.0f, 0.0f, 0.0f, 0.0f);
#pragma unroll
        for (int k = 0; k < 32; ++k) {
            float4 e, s;
            step_fast(mem.x, w1.x, k, w01, e.x, s.x);
            step_fast(mem.y, w1.y, k, w01, e.y, s.y);
            step_fast(mem.z, w1.z, k, w01, e.z, s.z);
            step_fast(mem.w, w1.w, k, w01, e.w, s.w);
            size_t idx = base + (size_t)k * B_SIZE;
            *(float4*)&spk_o[idx] = s;
            *(float4*)&exc_o[idx] = e;
            *(float4*)&inh_o[idx] = zero;             // w_inh * inh == +0
            *(float4*)&mem_o[idx] = mem;
        }
    } else {
        float4 inh = *(const float4*)&inh_ck[slot];
        uint4 w0 = *(const uint4*)&p0[slot];
        uint4 w1 = *(const uint4*)&p1[slot];
#pragma unroll
        for (int k = 0; k < 32; ++k) {
            float4 e, c, s;
            step_gen(mem.x, inh.x, w0.x, w1.x, k, w00, w01, winh, e.x, c.x, s.x);
            step_gen(mem.y, inh.y, w0.y, w1.y, k, w00, w01, winh, e.y, c.y, s.y);
            step_gen(mem.z, inh.z, w0.z, w1.z, k, w00, w01, winh, e.z, c.z, s.z);
            step_gen(mem.w, inh.w, w0.w, w1.w, k, w00, w01, winh, e.w, c.w, s.w);
            size_t idx = base + (size_t)k * B_SIZE;
            *(float4*)&spk_o[idx] = s;
            *(float4*)&exc_o[idx] = e;
            *(float4*)&inh_o[idx] = c;
            *(float4*)&mem_o[idx] = mem;
        }
    }
}

// ===========================================================================
// Fallback (harness-verified in R4 at 425.09 us): workspace-free pipeline,
// scratch stashed at the t=32*i rows of each output record (stride CKS).
// Each K2 thread reads only its own slots before its k=0 stores overwrite
// them -> race-free under stream ordering. NO __restrict__ on aliasable ptrs.
// ===========================================================================
#define CKS (32u * B_SIZE)

__global__ __launch_bounds__(256) void k_pack_fb(const float4* __restrict__ x,
                                                 uint32_t* __restrict__ p0,
                                                 uint32_t* __restrict__ p1) {
    uint32_t gid = blockIdx.x * 256u + threadIdx.x;
    uint32_t i  = gid >> 11;
    uint32_t bh = gid & (B_SIZE / 2 - 1);
    const float4* xp = x + (size_t)i * 32u * (B_SIZE / 2) + bh;
    uint32_t a0 = 0u, a1 = 0u, b0 = 0u, b1 = 0u;
#pragma unroll
    for (int k = 0; k < 32; ++k) {
        float4 v = xp[(size_t)k * (B_SIZE / 2)];
        a0 |= (uint32_t)(v.x != 0.0f) << k;
        a1 |= (uint32_t)(v.y != 0.0f) << k;
        b0 |= (uint32_t)(v.z != 0.0f) << k;
        b1 |= (uint32_t)(v.w != 0.0f) << k;
    }
    size_t o = (size_t)i * CKS + 2u * bh;
    *(uint2*)&p0[o] = make_uint2(a0, b0);
    *(uint2*)&p1[o] = make_uint2(a1, b1);
}

__global__ __launch_bounds__(256) void k_scan_fb(const uint32_t* __restrict__ p0,
                                                 const uint32_t* __restrict__ p1,
                                                 const float* __restrict__ w_exc,
                                                 const float* __restrict__ w_inh_p,
                                                 float* __restrict__ mem_ck,
                                                 float* __restrict__ inh_ck) {
    int b = blockIdx.x * 256 + threadIdx.x;
    const float w00 = w_exc[0], w01 = w_exc[1], winh = w_inh_p[0];
    float mem = 0.0f, inh = 0.0f;
    if (w00 == 0.0f && winh == 0.0f) {
        uint32_t w1 = p1[b];
        for (int i = 0; i < NWORDS; ++i) {
            uint32_t w1n = (i + 1 < NWORDS) ? p1[(size_t)(i + 1) * CKS + b] : 0u;
            mem_ck[(size_t)i * CKS + b] = mem;
#pragma unroll
            for (int k = 0; k < 32; ++k) {
                float x1f = (float)((w1 >> k) & 1u);
                float r   = (mem > 1.0f) ? 1.0f : 0.0f;
                float m1  = __fmul_rn(0.9f, mem);
                float m2  = __fmaf_rn(x1f, w01, m1);
                mem       = __fsub_rn(m2, r);
            }
            w1 = w1n;
        }
    } else {
        uint32_t w0 = p0[b], w1 = p1[b];
        for (int i = 0; i < NWORDS; ++i) {
            uint32_t w0n = (i + 1 < NWORDS) ? p0[(size_t)(i + 1) * CKS + b] : 0u;
            uint32_t w1n = (i + 1 < NWORDS) ? p1[(size_t)(i + 1) * CKS + b] : 0u;
            mem_ck[(size_t)i * CKS + b] = mem;
            inh_ck[(size_t)i * CKS + b] = inh;
#pragma unroll
            for (int k = 0; k < 32; ++k) {
                float x0f = (float)((w0 >> k) & 1u);
                float x1f = (float)((w1 >> k) & 1u);
                float exc = __fadd_rn(__fmul_rn(x0f, w00), __fmul_rn(x1f, w01));
                inh       = __fadd_rn(__fmul_rn(0.6f, inh), x0f);
                float ci  = __fmul_rn(winh, inh);
                float cur = __fadd_rn(exc, ci);
                float r   = (mem > 1.0f) ? 1.0f : 0.0f;
                float m1  = __fmul_rn(0.9f, mem);
                float m2  = __fadd_rn(m1, cur);
                mem       = __fsub_rn(m2, r);
            }
            w0 = w0n; w1 = w1n;
        }
    }
}

__global__ __launch_bounds__(256) void k_replay_fb(const uint32_t* p0,
                                                   const uint32_t* p1,
                                                   const float* __restrict__ w_exc,
                                                   const float* __restrict__ w_inh_p,
                                                   const float* mem_ck,
                                                   const float* inh_ck,
                                                   float* out) {
    uint32_t gid = blockIdx.x * 256u + threadIdx.x;
    uint32_t i  = gid >> 10;
    uint32_t b  = (gid & (B_SIZE / 4 - 1)) * 4u;
    float* spk_o = out;
    float* exc_o = out + TB;
    float* inh_o = out + 2 * TB;
    float* mem_o = out + 3 * TB;
    const float w00 = w_exc[0], w01 = w_exc[1], winh = w_inh_p[0];
    size_t slot = (size_t)i * CKS + b;
    float4 mem  = *(const float4*)&mem_ck[slot];
    size_t base = (size_t)i * 32u * B_SIZE + b;
    if (w00 == 0.0f && winh == 0.0f) {
        uint4 w1 = *(const uint4*)&p1[slot];
        const float4 zero = make_float4(0.0f, 0.0f, 0.0f, 0.0f);
#pragma unroll
        for (int k = 0; k < 32; ++k) {
            float4 e, s;
            step_fast(mem.x, w1.x, k, w01, e.x, s.x);
            step_fast(mem.y, w1.y, k, w01, e.y, s.y);
            step_fast(mem.z, w1.z, k, w01, e.z, s.z);
            step_fast(mem.w, w1.w, k, w01, e.w, s.w);
            size_t idx = base + (size_t)k * B_SIZE;
            *(float4*)&spk_o[idx] = s;
            *(float4*)&exc_o[idx] = e;
            *(float4*)&inh_o[idx] = zero;
            *(float4*)&mem_o[idx] = mem;
        }
    } else {
        float4 inh = *(const float4*)&inh_ck[slot];
        uint4 w0 = *(const uint4*)&p0[slot];
        uint4 w1 = *(const uint4*)&p1[slot];
#pragma unroll
        for (int k = 0; k < 32; ++k) {
            float4 e, c, s;
            step_gen(mem.x, inh.x, w0.x, w1.x, k, w00, w01, winh, e.x, c.x, s.x);
            step_gen(mem.y, inh.y, w0.y, w1.y, k, w00, w01, winh, e.y, c.y, s.y);
            step_gen(mem.z, inh.z, w0.z, w1.z, k, w00, w01, winh, e.z, c.z, s.z);
            step_gen(mem.w, inh.w, w0.w, w1.w, k, w00, w01, winh, e.w, c.w, s.w);
            size_t idx = base + (size_t)k * B_SIZE;
            *(float4*)&spk_o[idx] = s;
            *(float4*)&exc_o[idx] = e;
            *(float4*)&inh_o[idx] = c;
            *(float4*)&mem_o[idx] = mem;
        }
    }
}

extern "C" void kernel_launch(void* const* d_in, const int* in_sizes, int n_in,
                              void* d_out, int out_size, void* d_ws, size_t ws_size,
                              hipStream_t stream) {
    const float4* x4    = (const float4*)d_in[0];   // (T,B,2) f32, read as pairs
    const float*  w_exc = (const float*)d_in[1];    // (1,2) f32
    const float*  w_inh = (const float*)d_in[2];    // scalar f32
    float* out = (float*)d_out;

    const size_t nw   = (size_t)NWORDS * B_SIZE;    // 512K elements per array
    const size_t need = nw * 16;                    // 8 MiB scratch

    if (ws_size >= need) {
        // Dense scratch in the provided workspace (ws use is free: the
        // harness re-poisons ws unconditionally — R3 vs R4 A/B).
        uint32_t* p0     = (uint32_t*)d_ws;
        uint32_t* p1     = p0 + nw;
        float*    mem_ck = (float*)(p1 + nw);
        float*    inh_ck = mem_ck + nw;
        k_pack<<<(NWORDS * (B_SIZE / 2)) / 256, 256, 0, stream>>>(x4, p0, p1);
        k_scan<<<B_SIZE / 256, 256, 0, stream>>>(p0, p1, w_exc, w_inh, mem_ck, inh_ck);
        k_replay<<<(NWORDS * (B_SIZE / 4)) / 256, 256, 0, stream>>>(p0, p1, w_exc, w_inh,
                                                                    mem_ck, inh_ck, out);
    } else {
        // Workspace-free fallback: scratch inside the output buffer.
        uint32_t* p0     = (uint32_t*)out;
        uint32_t* p1     = (uint32_t*)(out + TB);
        float*    inh_ck = out + 2 * TB;
        float*    mem_ck = out + 3 * TB;
        k_pack_fb<<<(NWORDS * (B_SIZE / 2)) / 256, 256, 0, stream>>>(x4, p0, p1);
        k_scan_fb<<<B_SIZE / 256, 256, 0, stream>>>(p0, p1, w_exc, w_inh, mem_ck, inh_ck);
        k_replay_fb<<<(NWORDS * (B_SIZE / 4)) / 256, 256, 0, stream>>>(p0, p1, w_exc, w_inh,
                                                                       mem_ck, inh_ck, out);
    }
}